// Round 6
// baseline (440.688 us; speedup 1.0000x reference)
//
#include <hip/hip_runtime.h>
#include <hip/hip_bf16.h>

// GraphConvolution: x[B,N,D] fp32, W[K,D,O] fp32, COO edges per support (fp32 vals).
// out[b][n][k*O+o] = sum_{edges (r=n,c) in k} val * (x[b][c][:] @ W[k][:,o])
constexpr int B = 16, N = 10000, D = 128, O = 64, K = 3, E = 160000;
constexpr int BO = B * O;   // 1024
constexpr int KO = K * O;   // 192
constexpr int BSPL = 4;     // b-splits per 16-row n-tile (gemm grid = N/16 * BSPL)
constexpr int BPB  = B / BSPL;  // 4 b's per gemm block
constexpr int G2 = 2;       // spmm bo-groups of 512 (dwordx4/lane: 8 bo per lane)
constexpr int ROWS = 8;     // rows per spmm block
constexpr int NCH = N / ROWS;  // 1250

using short8  = __attribute__((ext_vector_type(8))) short;
using floatx4 = __attribute__((ext_vector_type(4))) float;
using f32x2   = __attribute__((ext_vector_type(2))) float;
using uint4v  = __attribute__((ext_vector_type(4))) unsigned;
struct U4 { unsigned a, b, c, d; };

__device__ __forceinline__ float bf2f(unsigned short u) {
  return __uint_as_float(((unsigned int)u) << 16);
}
// fp32 -> bf16, round-half-up (wpack only)
__device__ __forceinline__ unsigned short f2bf(float f) {
  return (unsigned short)((__float_as_uint(f) + 0x8000u) >> 16);
}
// packed fp32x2 -> bf16x2 (RNE), 1 VALU instead of 5
__device__ __forceinline__ unsigned cvtpk(float lo, float hi) {
  unsigned r;
  asm("v_cvt_pk_bf16_f32 %0, %1, %2" : "=v"(r) : "v"(lo), "v"(hi));
  return r;
}

// ---------------------------------------------------------------------------
// Kernel 0: repack W[K,D,O] fp32 -> MFMA A-fragment order (m=o, k=d), bf16.
// ---------------------------------------------------------------------------
__global__ void wpack_kernel(const float* __restrict__ w, unsigned short* __restrict__ wp) {
  const int i = blockIdx.x * 64 + threadIdx.x;
  if (i >= K * 16 * 64) return;
  const int lane = i & 63;
  const int dd = (i >> 6) & 3;
  const int t4 = (i >> 8) & 3;
  const int k  = i >> 10;
  const int o  = t4 * 16 + (lane & 15);
  const int d0 = dd * 32 + (lane >> 4) * 8;
  unsigned short* dst = wp + (size_t)i * 8;
#pragma unroll
  for (int j = 0; j < 8; ++j)
    dst[j] = f2bf(w[((size_t)k * D + d0 + j) * O + o]);
}

// ---------------------------------------------------------------------------
// Kernel 1: MFMA GEMM. pre[kloc][n][b*64+o] = sum_d x[b][n][d]*W[k][d][o] (bf16)
// A = W-frag (m=o), B = x-frag with n-axis = 16 CONSECUTIVE n (same b).
// ---------------------------------------------------------------------------
__global__ __launch_bounds__(192) void gemm_mfma_kernel(
    const float* __restrict__ x, const unsigned short* __restrict__ wpk,
    unsigned short* __restrict__ pre, int kBase)
{
  const int t = threadIdx.x;
  const int kloc = t >> 6;
  const int k = kBase + kloc;
  const int lane = t & 63;
  const int col  = lane & 15;   // n-axis of the B fragment
  const int quad = lane >> 4;

  short8 wfr[4][4];             // [t4][dd]
#pragma unroll
  for (int t4 = 0; t4 < 4; ++t4)
#pragma unroll
    for (int dd = 0; dd < 4; ++dd)
      wfr[t4][dd] = *(const short8*)(wpk + (size_t)(((k * 4 + t4) * 4 + dd) * 64 + lane) * 8);

  const int n0 = (blockIdx.x / BSPL) * 16;
  const int b0 = (blockIdx.x % BSPL) * BPB;
  const int n  = n0 + col;

  for (int bb = 0; bb < BPB; ++bb) {
    const int b = b0 + bb;
    const float* xp = x + ((size_t)b * N + n) * D + quad * 8;
    short8 xfr[4];
#pragma unroll
    for (int dd = 0; dd < 4; ++dd) {
      const float4 lo = *(const float4*)(xp + dd * 32);
      const float4 hi = *(const float4*)(xp + dd * 32 + 4);
      U4 u;
      u.a = cvtpk(lo.x, lo.y); u.b = cvtpk(lo.z, lo.w);
      u.c = cvtpk(hi.x, hi.y); u.d = cvtpk(hi.z, hi.w);
      xfr[dd] = __builtin_bit_cast(short8, u);
    }

    floatx4 acc[4] = {};
#pragma unroll
    for (int dd = 0; dd < 4; ++dd)
#pragma unroll
      for (int t4 = 0; t4 < 4; ++t4)
        acc[t4] = __builtin_amdgcn_mfma_f32_16x16x32_bf16(wfr[t4][dd], xfr[dd], acc[t4], 0, 0, 0);

    // D layout: col(lane&15)=n-axis, row(quad*4+j)=o-axis
    unsigned short* pp = pre + (((size_t)kloc * N + n) << 10) + b * 64 + quad * 4;
#pragma unroll
    for (int t4 = 0; t4 < 4; ++t4) {
      uint2 pk2;
      pk2.x = cvtpk(acc[t4][0], acc[t4][1]);
      pk2.y = cvtpk(acc[t4][2], acc[t4][3]);
      *(uint2*)(pp + t4 * 16) = pk2;
    }
  }
}

// ---------------------------------------------------------------------------
// Kernel 2: per-row edge histogram
// ---------------------------------------------------------------------------
__global__ void hist_kernel(const int* __restrict__ row, int* __restrict__ cnt) {
  const int i = blockIdx.x * 256 + threadIdx.x;
  if (i >= K * E) return;
  const int k = i / E;
  atomicAdd(&cnt[k * N + row[i]], 1);
}

// ---------------------------------------------------------------------------
// Kernel 3: exclusive scan per support -> CSR offsets (cnt becomes cursor)
// ---------------------------------------------------------------------------
__global__ __launch_bounds__(1024) void scan_kernel(int* __restrict__ cnt,
                                                    int* __restrict__ offs) {
  const int k = blockIdx.x;
  const int t = threadIdx.x;
  const int lane = t & 63, wid = t >> 6;
  __shared__ int wt[16];
  __shared__ int sbase;
  if (t == 0) { sbase = 0; offs[k * (N + 1)] = 0; }
  __syncthreads();

  for (int c0 = 0; c0 < N; c0 += 1024) {
    const int i = c0 + t;
    const int v = (i < N) ? cnt[k * N + i] : 0;
    int incl = v;
#pragma unroll
    for (int st = 1; st < 64; st <<= 1) {
      const int u = __shfl_up(incl, st, 64);
      if (lane >= st) incl += u;
    }
    if (lane == 63) wt[wid] = incl;
    __syncthreads();
    if (wid == 0) {
      int wv = (lane < 16) ? wt[lane] : 0;
#pragma unroll
      for (int st = 1; st < 16; st <<= 1) {
        const int u = __shfl_up(wv, st, 64);
        if (lane >= st) wv += u;
      }
      if (lane < 16) wt[lane] = wv;
    }
    __syncthreads();
    const int base = sbase + ((wid > 0) ? wt[wid - 1] : 0);
    if (i < N) {
      offs[k * (N + 1) + i + 1] = base + incl;
      cnt[k * N + i] = base + incl - v;
    }
    __syncthreads();
    if (t == 0) sbase += wt[15];
    __syncthreads();
  }
}

// ---------------------------------------------------------------------------
// Kernel 4: scatter edges into CSR order
// ---------------------------------------------------------------------------
__global__ void scatter_kernel(const int* __restrict__ row, const int* __restrict__ col,
                               const float* __restrict__ vals,
                               int* __restrict__ cursor, int* __restrict__ scol,
                               float* __restrict__ sval) {
  const int i = blockIdx.x * 256 + threadIdx.x;
  if (i >= K * E) return;
  const int k = i / E;
  const int pos = atomicAdd(&cursor[k * N + row[i]], 1);
  scol[k * E + pos] = col[i];
  sval[k * E + pos] = vals[i];
}

// ---------------------------------------------------------------------------
// Kernel 5: CSR SpMM — wide-gather variant. Round 5 showed the limiter is the
// per-CU outstanding-VMEM-instruction budget (9.4 TB/s gather throughput vs
// ~40 TB/s Little's-law nominal): each slot carried only 256B. Now each lane
// loads dwordx4 (16B = 8 bo), a wave covers 512 bo, G=2 groups per row:
// per edge 2 wave-instrs chip-wide instead of 8 -> 4x fewer VMEM instrs,
// 4x more bytes per vmcnt slot, and aggregate pre cache demand drops
// 492 MB -> 123 MB. k-major block order; 8-deep edge pipeline (8KB in
// flight per wave); plain loads for edge data; nt stores for out.
// ---------------------------------------------------------------------------
__global__ __launch_bounds__(64) void spmm_kernel(
    const unsigned short* __restrict__ pre, const int* __restrict__ offs,
    const int* __restrict__ scol, const float* __restrict__ sval,
    float* __restrict__ out, int kBase)
{
  const int bid = blockIdx.x;
  const int g   = bid & (G2 - 1);
  const int t2  = bid >> 1;
  const int nc  = t2 % NCH;
  const int kloc = t2 / NCH;            // k-major: all nc for k before k+1
  const int k = kBase + kloc;
  const int lane = threadIdx.x;

  const int bo = g * 512 + lane * 8;    // 8 consecutive bo per lane (16B)
  const int b = bo >> 6;
  const int o = bo & 63;
  const unsigned short* pk = pre + (((size_t)kloc * N) << 10) + bo;
  const int* cj = scol + (size_t)k * E;
  const float* vj = sval + (size_t)k * E;
  const int* op = offs + k * (N + 1) + nc * ROWS;

  int ofs[ROWS + 1];
#pragma unroll
  for (int r = 0; r <= ROWS; ++r) ofs[r] = __builtin_amdgcn_readfirstlane(op[r]);

  float* outp = out + ((size_t)b * N + nc * ROWS) * KO + (size_t)k * O + o;

  for (int r = 0; r < ROWS; ++r) {
    const int j0 = ofs[r];
    const int j1 = ofs[r + 1];
    float a0 = 0.f, a1 = 0.f, a2 = 0.f, a3 = 0.f;
    float a4 = 0.f, a5 = 0.f, a6 = 0.f, a7 = 0.f;
    int j = j0;
    // 8 edges (8KB) in flight per wave
    for (; j + 7 < j1; j += 8) {
      uint4v u[8]; float v[8];
#pragma unroll
      for (int i = 0; i < 8; ++i) {
        const int c2 = __builtin_amdgcn_readfirstlane(cj[j + i]);  // SGPR offset
        u[i] = *(const uint4v*)(pk + ((size_t)c2 << 10));
        v[i] = vj[j + i];
      }
#pragma unroll
      for (int i = 0; i < 8; ++i) {
        a0 += v[i] * __uint_as_float(u[i][0] << 16);
        a1 += v[i] * __uint_as_float(u[i][0] & 0xFFFF0000u);
        a2 += v[i] * __uint_as_float(u[i][1] << 16);
        a3 += v[i] * __uint_as_float(u[i][1] & 0xFFFF0000u);
        a4 += v[i] * __uint_as_float(u[i][2] << 16);
        a5 += v[i] * __uint_as_float(u[i][2] & 0xFFFF0000u);
        a6 += v[i] * __uint_as_float(u[i][3] << 16);
        a7 += v[i] * __uint_as_float(u[i][3] & 0xFFFF0000u);
      }
    }
    for (; j < j1; ++j) {
      const int c2 = __builtin_amdgcn_readfirstlane(cj[j]);
      const float v = vj[j];
      const uint4v u = *(const uint4v*)(pk + ((size_t)c2 << 10));
      a0 += v * __uint_as_float(u[0] << 16);
      a1 += v * __uint_as_float(u[0] & 0xFFFF0000u);
      a2 += v * __uint_as_float(u[1] << 16);
      a3 += v * __uint_as_float(u[1] & 0xFFFF0000u);
      a4 += v * __uint_as_float(u[2] << 16);
      a5 += v * __uint_as_float(u[2] & 0xFFFF0000u);
      a6 += v * __uint_as_float(u[3] << 16);
      a7 += v * __uint_as_float(u[3] & 0xFFFF0000u);
    }
    floatx4 lo4; lo4[0] = a0; lo4[1] = a1; lo4[2] = a2; lo4[3] = a3;
    floatx4 hi4; hi4[0] = a4; hi4[1] = a5; hi4[2] = a6; hi4[3] = a7;
    // write-only stream: nt stores keep L2 for pre (32B-aligned)
    __builtin_nontemporal_store(lo4, (floatx4*)(outp));
    __builtin_nontemporal_store(hi4, (floatx4*)(outp + 4));
    outp += KO;
  }
}

// ---------------------------------------------------------------------------
extern "C" void kernel_launch(void* const* d_in, const int* in_sizes, int n_in,
                              void* d_out, int out_size, void* d_ws, size_t ws_size,
                              hipStream_t stream) {
  const float* x    = (const float*)d_in[0];
  const float* w    = (const float*)d_in[1];
  const float* vals = (const float*)d_in[2];
  const int* row    = (const int*)d_in[3];
  const int* col    = (const int*)d_in[4];
  float* out        = (float*)d_out;

  char* p = (char*)d_ws;
  int* offs = (int*)p;            p += ((size_t)K * (N + 1) * 4 + 15) & ~(size_t)15;
  int* cnt  = (int*)p;            p += (size_t)K * N * 4;
  int* scol = (int*)p;            p += (size_t)K * E * 4;
  float* sval = (float*)p;        p += (size_t)K * E * 4;
  unsigned short* wpk = (unsigned short*)p; p += (size_t)K * 16 * 64 * 8 * 2;
  unsigned short* pre = (unsigned short*)p;
  const size_t fixed = (size_t)(p - (char*)d_ws);
  const size_t preFull = (size_t)K * N * BO * 2;
  const bool full = ws_size >= fixed + preFull;  // ws_size constant across calls

  hipMemsetAsync(cnt, 0, (size_t)K * N * 4, stream);

  wpack_kernel<<<48, 64, 0, stream>>>(w, wpk);
  const int eb = (K * E + 255) / 256;
  hist_kernel<<<eb, 256, 0, stream>>>(row, cnt);
  scan_kernel<<<K, 1024, 0, stream>>>(cnt, offs);
  scatter_kernel<<<eb, 256, 0, stream>>>(row, col, vals, cnt, scol, sval);

  if (full) {
    gemm_mfma_kernel<<<(N / 16) * BSPL, 64 * K, 0, stream>>>(x, wpk, pre, 0);
    spmm_kernel<<<K * NCH * G2, 64, 0, stream>>>(pre, offs, scol, sval, out, 0);
  } else {
    for (int k = 0; k < K; ++k) {
      gemm_mfma_kernel<<<(N / 16) * BSPL, 64, 0, stream>>>(x, wpk, pre, k);
      spmm_kernel<<<NCH * G2, 64, 0, stream>>>(pre, offs, scol, sval, out, k);
    }
  }
  (void)in_sizes; (void)n_in; (void)out_size;
}

// Round 7
// 408.203 us; speedup vs baseline: 1.0796x; 1.0796x over previous
//
#include <hip/hip_runtime.h>
#include <hip/hip_bf16.h>

// GraphConvolution: x[B,N,D] fp32, W[K,D,O] fp32, COO edges per support (fp32 vals).
// out[b][n][k*O+o] = sum_{edges (r=n,c) in k} val * (x[b][c][:] @ W[k][:,o])
constexpr int B = 16, N = 10000, D = 128, O = 64, K = 3, E = 160000;
constexpr int BO = B * O;   // 1024
constexpr int KO = K * O;   // 192
constexpr int BSPL = 4;     // b-splits per 16-row n-tile (gemm grid = N/16 * BSPL)
constexpr int BPB  = B / BSPL;  // 4 b's per gemm block
constexpr int G = 8;        // spmm bo-groups (256B slice per wave-gather: proven best)
constexpr int ROWS = 8;     // rows per spmm block
constexpr int NCH = N / ROWS;  // 1250

using short8  = __attribute__((ext_vector_type(8))) short;
using floatx4 = __attribute__((ext_vector_type(4))) float;
using f32x2   = __attribute__((ext_vector_type(2))) float;
struct U4 { unsigned a, b, c, d; };

__device__ __forceinline__ float bf2f(unsigned short u) {
  return __uint_as_float(((unsigned int)u) << 16);
}
// fp32 -> bf16, round-half-up (wpack only)
__device__ __forceinline__ unsigned short f2bf(float f) {
  return (unsigned short)((__float_as_uint(f) + 0x8000u) >> 16);
}
// packed fp32x2 -> bf16x2 (RNE), 1 VALU instead of 5
__device__ __forceinline__ unsigned cvtpk(float lo, float hi) {
  unsigned r;
  asm("v_cvt_pk_bf16_f32 %0, %1, %2" : "=v"(r) : "v"(lo), "v"(hi));
  return r;
}

// ---------------------------------------------------------------------------
// Kernel 0: repack W[K,D,O] fp32 -> MFMA A-fragment order (m=o, k=d), bf16.
// ---------------------------------------------------------------------------
__global__ void wpack_kernel(const float* __restrict__ w, unsigned short* __restrict__ wp) {
  const int i = blockIdx.x * 64 + threadIdx.x;
  if (i >= K * 16 * 64) return;
  const int lane = i & 63;
  const int dd = (i >> 6) & 3;
  const int t4 = (i >> 8) & 3;
  const int k  = i >> 10;
  const int o  = t4 * 16 + (lane & 15);
  const int d0 = dd * 32 + (lane >> 4) * 8;
  unsigned short* dst = wp + (size_t)i * 8;
#pragma unroll
  for (int j = 0; j < 8; ++j)
    dst[j] = f2bf(w[((size_t)k * D + d0 + j) * O + o]);
}

// ---------------------------------------------------------------------------
// Kernel 1: MFMA GEMM. pre[kloc][n][b*64+o] = sum_d x[b][n][d]*W[k][d][o] (bf16)
// A = W-frag (m=o), B = x-frag with n-axis = 16 CONSECUTIVE n (same b).
// ---------------------------------------------------------------------------
__global__ __launch_bounds__(192) void gemm_mfma_kernel(
    const float* __restrict__ x, const unsigned short* __restrict__ wpk,
    unsigned short* __restrict__ pre, int kBase)
{
  const int t = threadIdx.x;
  const int kloc = t >> 6;
  const int k = kBase + kloc;
  const int lane = t & 63;
  const int col  = lane & 15;   // n-axis of the B fragment
  const int quad = lane >> 4;

  short8 wfr[4][4];             // [t4][dd]
#pragma unroll
  for (int t4 = 0; t4 < 4; ++t4)
#pragma unroll
    for (int dd = 0; dd < 4; ++dd)
      wfr[t4][dd] = *(const short8*)(wpk + (size_t)(((k * 4 + t4) * 4 + dd) * 64 + lane) * 8);

  const int n0 = (blockIdx.x / BSPL) * 16;
  const int b0 = (blockIdx.x % BSPL) * BPB;
  const int n  = n0 + col;

  for (int bb = 0; bb < BPB; ++bb) {
    const int b = b0 + bb;
    const float* xp = x + ((size_t)b * N + n) * D + quad * 8;
    short8 xfr[4];
#pragma unroll
    for (int dd = 0; dd < 4; ++dd) {
      const float4 lo = *(const float4*)(xp + dd * 32);
      const float4 hi = *(const float4*)(xp + dd * 32 + 4);
      U4 u;
      u.a = cvtpk(lo.x, lo.y); u.b = cvtpk(lo.z, lo.w);
      u.c = cvtpk(hi.x, hi.y); u.d = cvtpk(hi.z, hi.w);
      xfr[dd] = __builtin_bit_cast(short8, u);
    }

    floatx4 acc[4] = {};
#pragma unroll
    for (int dd = 0; dd < 4; ++dd)
#pragma unroll
      for (int t4 = 0; t4 < 4; ++t4)
        acc[t4] = __builtin_amdgcn_mfma_f32_16x16x32_bf16(wfr[t4][dd], xfr[dd], acc[t4], 0, 0, 0);

    // D layout: col(lane&15)=n-axis, row(quad*4+j)=o-axis
    unsigned short* pp = pre + (((size_t)kloc * N + n) << 10) + b * 64 + quad * 4;
#pragma unroll
    for (int t4 = 0; t4 < 4; ++t4) {
      uint2 pk2;
      pk2.x = cvtpk(acc[t4][0], acc[t4][1]);
      pk2.y = cvtpk(acc[t4][2], acc[t4][3]);
      *(uint2*)(pp + t4 * 16) = pk2;
    }
  }
}

// ---------------------------------------------------------------------------
// Kernel 2: per-row edge histogram
// ---------------------------------------------------------------------------
__global__ void hist_kernel(const int* __restrict__ row, int* __restrict__ cnt) {
  const int i = blockIdx.x * 256 + threadIdx.x;
  if (i >= K * E) return;
  const int k = i / E;
  atomicAdd(&cnt[k * N + row[i]], 1);
}

// ---------------------------------------------------------------------------
// Kernel 3: exclusive scan per support -> CSR offsets (cnt becomes cursor)
// ---------------------------------------------------------------------------
__global__ __launch_bounds__(1024) void scan_kernel(int* __restrict__ cnt,
                                                    int* __restrict__ offs) {
  const int k = blockIdx.x;
  const int t = threadIdx.x;
  const int lane = t & 63, wid = t >> 6;
  __shared__ int wt[16];
  __shared__ int sbase;
  if (t == 0) { sbase = 0; offs[k * (N + 1)] = 0; }
  __syncthreads();

  for (int c0 = 0; c0 < N; c0 += 1024) {
    const int i = c0 + t;
    const int v = (i < N) ? cnt[k * N + i] : 0;
    int incl = v;
#pragma unroll
    for (int st = 1; st < 64; st <<= 1) {
      const int u = __shfl_up(incl, st, 64);
      if (lane >= st) incl += u;
    }
    if (lane == 63) wt[wid] = incl;
    __syncthreads();
    if (wid == 0) {
      int wv = (lane < 16) ? wt[lane] : 0;
#pragma unroll
      for (int st = 1; st < 16; st <<= 1) {
        const int u = __shfl_up(wv, st, 64);
        if (lane >= st) wv += u;
      }
      if (lane < 16) wt[lane] = wv;
    }
    __syncthreads();
    const int base = sbase + ((wid > 0) ? wt[wid - 1] : 0);
    if (i < N) {
      offs[k * (N + 1) + i + 1] = base + incl;
      cnt[k * N + i] = base + incl - v;
    }
    __syncthreads();
    if (t == 0) sbase += wt[15];
    __syncthreads();
  }
}

// ---------------------------------------------------------------------------
// Kernel 4: scatter edges into CSR order
// ---------------------------------------------------------------------------
__global__ void scatter_kernel(const int* __restrict__ row, const int* __restrict__ col,
                               const float* __restrict__ vals,
                               int* __restrict__ cursor, int* __restrict__ scol,
                               float* __restrict__ sval) {
  const int i = blockIdx.x * 256 + threadIdx.x;
  if (i >= K * E) return;
  const int k = i / E;
  const int pos = atomicAdd(&cursor[k * N + row[i]], 1);
  scol[k * E + pos] = col[i];
  sval[k * E + pos] = vals[i];
}

// ---------------------------------------------------------------------------
// Kernel 5: CSR SpMM — round-5 proven structure (G=8 256B wave-gathers,
// 16-deep unroll, 1-wave blocks), now launched PER SUPPORT: grid = NCH*G,
// one k per dispatch. Only one 20.5MB pre k-slice is hot per dispatch
// (fits aggregate L2), and each dispatch drops below the gemm's duration
// so the hidden non-spmm kernels finally surface in the profile top-5.
// Round-6's dwordx4/G=2 variant REFUTED (FETCH doubled: cross-XCD slice
// spread destroyed L2 reuse) — do not revisit.
// ---------------------------------------------------------------------------
__global__ __launch_bounds__(64) void spmm_kernel(
    const unsigned short* __restrict__ pre, const int* __restrict__ offs,
    const int* __restrict__ scol, const float* __restrict__ sval,
    float* __restrict__ out, int k, int preSlice)
{
  const int bid = blockIdx.x;
  const int g   = bid & 7;
  const int nc  = bid >> 3;
  const int lane = threadIdx.x;

  const int bo = g * 128 + 2 * lane;    // 2 consecutive bo per lane
  const int b = bo >> 6;
  const int o = bo & 63;
  const unsigned short* pk = pre + (((size_t)preSlice * N) << 10) + bo;
  const int* cj = scol + (size_t)k * E;
  const float* vj = sval + (size_t)k * E;
  const int* op = offs + k * (N + 1) + nc * ROWS;

  int ofs[ROWS + 1];
#pragma unroll
  for (int r = 0; r <= ROWS; ++r) ofs[r] = __builtin_amdgcn_readfirstlane(op[r]);

  for (int r = 0; r < ROWS; ++r) {
    const int j0 = ofs[r];
    const int j1 = ofs[r + 1];
    float a0 = 0.f, a1 = 0.f;
    int j = j0;
    // 16 gathers in flight
    for (; j + 15 < j1; j += 16) {
      unsigned u[16]; float v[16];
#pragma unroll
      for (int i = 0; i < 16; ++i) {
        const int c2 = __builtin_amdgcn_readfirstlane(cj[j + i]);  // SGPR base
        u[i] = *(const unsigned*)(pk + ((size_t)c2 << 10));
        v[i] = vj[j + i];
      }
#pragma unroll
      for (int i = 0; i < 16; ++i) {
        a0 += v[i] * bf2f((unsigned short)(u[i] & 0xFFFFu));
        a1 += v[i] * bf2f((unsigned short)(u[i] >> 16));
      }
    }
    for (; j + 7 < j1; j += 8) {
      unsigned u[8]; float v[8];
#pragma unroll
      for (int i = 0; i < 8; ++i) {
        const int c2 = __builtin_amdgcn_readfirstlane(cj[j + i]);
        u[i] = *(const unsigned*)(pk + ((size_t)c2 << 10));
        v[i] = vj[j + i];
      }
#pragma unroll
      for (int i = 0; i < 8; ++i) {
        a0 += v[i] * bf2f((unsigned short)(u[i] & 0xFFFFu));
        a1 += v[i] * bf2f((unsigned short)(u[i] >> 16));
      }
    }
    for (; j < j1; ++j) {
      const int c2 = __builtin_amdgcn_readfirstlane(cj[j]);
      const float v = vj[j];
      const unsigned u = *(const unsigned*)(pk + ((size_t)c2 << 10));
      a0 += v * bf2f((unsigned short)(u & 0xFFFFu));
      a1 += v * bf2f((unsigned short)(u >> 16));
    }
    const int n = nc * ROWS + r;
    f32x2 st; st.x = a0; st.y = a1;
    // write-only stream: nt store keeps L2 for pre
    __builtin_nontemporal_store(st,
        (f32x2*)(out + ((size_t)b * N + n) * KO + (size_t)k * O + o));
  }
}

// ---------------------------------------------------------------------------
extern "C" void kernel_launch(void* const* d_in, const int* in_sizes, int n_in,
                              void* d_out, int out_size, void* d_ws, size_t ws_size,
                              hipStream_t stream) {
  const float* x    = (const float*)d_in[0];
  const float* w    = (const float*)d_in[1];
  const float* vals = (const float*)d_in[2];
  const int* row    = (const int*)d_in[3];
  const int* col    = (const int*)d_in[4];
  float* out        = (float*)d_out;

  char* p = (char*)d_ws;
  int* offs = (int*)p;            p += ((size_t)K * (N + 1) * 4 + 15) & ~(size_t)15;
  int* cnt  = (int*)p;            p += (size_t)K * N * 4;
  int* scol = (int*)p;            p += (size_t)K * E * 4;
  float* sval = (float*)p;        p += (size_t)K * E * 4;
  unsigned short* wpk = (unsigned short*)p; p += (size_t)K * 16 * 64 * 8 * 2;
  unsigned short* pre = (unsigned short*)p;
  const size_t fixed = (size_t)(p - (char*)d_ws);
  const size_t preFull = (size_t)K * N * BO * 2;
  const bool full = ws_size >= fixed + preFull;  // ws_size constant across calls

  hipMemsetAsync(cnt, 0, (size_t)K * N * 4, stream);

  wpack_kernel<<<48, 64, 0, stream>>>(w, wpk);
  const int eb = (K * E + 255) / 256;
  hist_kernel<<<eb, 256, 0, stream>>>(row, cnt);
  scan_kernel<<<K, 1024, 0, stream>>>(cnt, offs);
  scatter_kernel<<<eb, 256, 0, stream>>>(row, col, vals, cnt, scol, sval);

  if (full) {
    gemm_mfma_kernel<<<(N / 16) * BSPL, 64 * K, 0, stream>>>(x, wpk, pre, 0);
    for (int k = 0; k < K; ++k)
      spmm_kernel<<<NCH * G, 64, 0, stream>>>(pre, offs, scol, sval, out, k, k);
  } else {
    for (int k = 0; k < K; ++k) {
      gemm_mfma_kernel<<<(N / 16) * BSPL, 64, 0, stream>>>(x, wpk, pre, k);
      spmm_kernel<<<NCH * G, 64, 0, stream>>>(pre, offs, scol, sval, out, k, 0);
    }
  }
  (void)in_sizes; (void)n_in; (void)out_size;
}